// Round 4
// baseline (614.828 us; speedup 1.0000x reference)
//
#include <hip/hip_runtime.h>

// ---------------------------------------------------------------------------
// Spatial transformer loc-net + bilinear sampler. N=16384, x:[N,1,28,28] f32.
// R2: single-pass convs (sign(BN scale)=sign(gamma) known a priori -> store
//     pooled extremum raw, finalize affine+relu in a memory-bound pass).
// R3: fix k_init race — zero ONLY the stats region [0,104); in R2 the zeroing
//     range [0,512) overlapped the w2-transpose region [104,2104) within one
//     kernel -> undefined order -> corrupted conv2 weights (absmax 5.05).
// ---------------------------------------------------------------------------

static constexpr float kEPS = 1e-5f;

// ws float offsets
#define O_SUM1 0
#define O_SSQ1 8
#define O_SUM2 16
#define O_SSQ2 26
#define O_MOM  36      // 10 means + 55 upper-tri second moments of pool2
#define O_W2T  104             // 2000 floats: w2 as [oc][ky][kx][ic]
#define O_THETA 2112           // 16384*6
#define O_E1   100864          // [N][11][11][8] extremes -> pool1 in place
#define O_E2   15960576        // [N][9][10]    extremes -> pool2 in place
// high-water: 17,435,136 floats = 69.7 MB

__global__ __launch_bounds__(256) void k_init(const float* __restrict__ w2,
                                              float* __restrict__ ws){
  int i = blockIdx.x*256 + threadIdx.x;
  if (i < 104) ws[i] = 0.f;            // stats region only — MUST not touch W2T
  if (i < 2000){
    int ic = i & 7;
    int r  = i >> 3;
    int kx = r % 5; r /= 5;
    int ky = r % 5; r /= 5;
    int oc = r;
    ws[O_W2T + i] = w2[(oc*8 + ic)*25 + ky*5 + kx];
  }
}

// conv1 7x7 [N,1,28,28]->[N,8,22,22], single pass: BN1 stats + signed pooled
// extremum -> E1 [N][11][11][8] (ic innermost).
__global__ __launch_bounds__(256, 4) void k_conv1(const float* __restrict__ x,
                                                  const float* __restrict__ w1,
                                                  const float* __restrict__ g1,
                                                  float* __restrict__ ws){
  const int tid = threadIdx.x;
  const int gid = blockIdx.x*256 + tid;
  const int ph = gid & 1;          // which half of the 11 pooled rows
  const int c  = (gid >> 1) & 7;
  const int n  = gid >> 4;
  const float* __restrict__ xs = x + n*784;
  float w[49];
  #pragma unroll
  for (int i=0;i<49;i++) w[i] = w1[c*49+i];
  const bool pos = (g1[c] >= 0.f);
  float sum=0.f, ssq=0.f;
  float* __restrict__ outp = ws + O_E1 + n*968 + c;   // interleaved base
  const int p0 = ph*6;
  const int p1 = ph ? 11 : 6;
  for (int p=p0; p<p1; p++){
    float a0[22], a1[22];
    #pragma unroll
    for (int i=0;i<22;i++){ a0[i]=0.f; a1[i]=0.f; }
    #pragma unroll
    for (int j=0;j<8;j++){            // input rows 2p..2p+7 feed conv rows 2p,2p+1
      float in[28];
      const float4* __restrict__ rp = (const float4*)(xs + (2*p+j)*28);
      #pragma unroll
      for (int q=0;q<7;q++){
        float4 v = rp[q];
        in[4*q]=v.x; in[4*q+1]=v.y; in[4*q+2]=v.z; in[4*q+3]=v.w;
      }
      if (j < 7){                     // ky = j for conv row 2p
        #pragma unroll
        for (int kx=0;kx<7;kx++){
          float wv = w[j*7+kx];
          #pragma unroll
          for (int xo=0;xo<22;xo++) a0[xo] = fmaf(wv, in[xo+kx], a0[xo]);
        }
      }
      if (j >= 1){                    // ky = j-1 for conv row 2p+1
        #pragma unroll
        for (int kx=0;kx<7;kx++){
          float wv = w[(j-1)*7+kx];
          #pragma unroll
          for (int xo=0;xo<22;xo++) a1[xo] = fmaf(wv, in[xo+kx], a1[xo]);
        }
      }
    }
    // stats over all conv outputs
    #pragma unroll
    for (int xo=0;xo<22;xo++){
      sum += a0[xo] + a1[xo];
      ssq = fmaf(a0[xo],a0[xo],ssq);
      ssq = fmaf(a1[xo],a1[xo],ssq);
    }
    // signed pooled extremum (sign of BN scale == sign of gamma, known now)
    #pragma unroll
    for (int px=0;px<11;px++){
      float m4 = fmaxf(fmaxf(a0[2*px],a0[2*px+1]), fmaxf(a1[2*px],a1[2*px+1]));
      float n4 = fminf(fminf(a0[2*px],a0[2*px+1]), fminf(a1[2*px],a1[2*px+1]));
      outp[(p*11+px)*8] = pos ? m4 : n4;
    }
  }
  // block-level stats reduction: lanes sharing c differ in bits {0,4,5}
  sum += __shfl_xor(sum,1);  ssq += __shfl_xor(ssq,1);
  sum += __shfl_xor(sum,16); ssq += __shfl_xor(ssq,16);
  sum += __shfl_xor(sum,32); ssq += __shfl_xor(ssq,32);
  __shared__ float ls[16];
  if (tid < 16) ls[tid] = 0.f;
  __syncthreads();
  int l = tid & 63;
  if ((l & 0x31) == 0){
    atomicAdd(&ls[l>>1], sum);
    atomicAdd(&ls[8 + (l>>1)], ssq);
  }
  __syncthreads();
  if (tid < 16) atomicAdd(&ws[O_SUM1 + tid], ls[tid]);
}

// in-place BN1 affine + relu on E1 -> pool1 [N][11][11][8]
__global__ __launch_bounds__(256) void k_pool1fin(float* __restrict__ ws,
                                                  const float* __restrict__ g1,
                                                  const float* __restrict__ b1){
  const float invM = 1.f/7929856.f;
  float4 sA, sB, tA, tB;
  {
    float s[8], t[8];
    #pragma unroll
    for (int c=0;c<8;c++){
      float mean = ws[O_SUM1+c]*invM;
      float var  = ws[O_SSQ1+c]*invM - mean*mean;
      float sc = g1[c]*rsqrtf(var + kEPS);
      s[c] = sc; t[c] = b1[c] - mean*sc;
    }
    sA = make_float4(s[0],s[1],s[2],s[3]); sB = make_float4(s[4],s[5],s[6],s[7]);
    tA = make_float4(t[0],t[1],t[2],t[3]); tB = make_float4(t[4],t[5],t[6],t[7]);
  }
  const int nf8 = 15859712/8;
  float4* __restrict__ p = (float4*)(ws + O_E1);
  for (int i = blockIdx.x*256 + threadIdx.x; i < nf8; i += gridDim.x*256){
    float4 v0 = p[2*i], v1 = p[2*i+1];
    v0.x = fmaxf(fmaf(sA.x, v0.x, tA.x), 0.f);
    v0.y = fmaxf(fmaf(sA.y, v0.y, tA.y), 0.f);
    v0.z = fmaxf(fmaf(sA.z, v0.z, tA.z), 0.f);
    v0.w = fmaxf(fmaf(sA.w, v0.w, tA.w), 0.f);
    v1.x = fmaxf(fmaf(sB.x, v1.x, tB.x), 0.f);
    v1.y = fmaxf(fmaf(sB.y, v1.y, tB.y), 0.f);
    v1.z = fmaxf(fmaf(sB.z, v1.z, tB.z), 0.f);
    v1.w = fmaxf(fmaf(sB.w, v1.w, tB.w), 0.f);
    p[2*i] = v0; p[2*i+1] = v1;
  }
}

// conv2 5x5 [N,8,11,11]->[N,10,7,7] from interleaved pool1, single pass:
// BN2 stats + signed pooled extremum -> E2 [N][9][10].
// Row-split: blocks<640 own conv rows 0..3, blocks>=640 own rows 4..6.
__global__ __launch_bounds__(256) void k_conv2(float* __restrict__ ws,
                                               const float* __restrict__ g2){
  const int blk = blockIdx.x;
  const int half = (blk >= 640) ? 1 : 0;
  const int gid = (blk - half*640)*256 + threadIdx.x;
  const int n = gid/10, oc = gid - 10*n;
  const int r0 = half*4;                 // first owned conv row
  const int nrows = half ? 7 : 8;        // input rows streamed
  const float* __restrict__ wt = ws + O_W2T + oc*200;
  const float* __restrict__ base = ws + O_E1 + n*968;   // pool1 (finalized)
  float acc[28];
  #pragma unroll
  for (int i=0;i<28;i++) acc[i]=0.f;
  for (int jj=0; jj<nrows; ++jj){        // uniform loop
    const int iy = r0 + jj;
    float in[88];
    const float4* __restrict__ rp = (const float4*)(base + iy*88);
    #pragma unroll
    for (int q=0;q<22;q++){
      float4 v = rp[q];
      in[4*q]=v.x; in[4*q+1]=v.y; in[4*q+2]=v.z; in[4*q+3]=v.w;
    }
    #pragma unroll
    for (int ol=0; ol<4; ++ol){          // owned conv row (local)
      if (half && ol==3) continue;       // half1 owns 3 rows
      const int ky = jj - ol;            // uniform at runtime
      if (ky < 0 || ky > 4) continue;
      const float* __restrict__ wrow = wt + ky*40;
      #pragma unroll
      for (int kx=0;kx<5;kx++){
        float4 wa = *(const float4*)(wrow + kx*8);
        float4 wb = *(const float4*)(wrow + kx*8 + 4);
        #pragma unroll
        for (int ox=0;ox<7;ox++){
          float a = acc[ol*7+ox];
          a = fmaf(wa.x, in[(ox+kx)*8+0], a);
          a = fmaf(wa.y, in[(ox+kx)*8+1], a);
          a = fmaf(wa.z, in[(ox+kx)*8+2], a);
          a = fmaf(wa.w, in[(ox+kx)*8+3], a);
          a = fmaf(wb.x, in[(ox+kx)*8+4], a);
          a = fmaf(wb.y, in[(ox+kx)*8+5], a);
          a = fmaf(wb.z, in[(ox+kx)*8+6], a);
          a = fmaf(wb.w, in[(ox+kx)*8+7], a);
          acc[ol*7+ox] = a;
        }
      }
    }
  }
  // stats over owned conv rows
  {
    const int NV = (half ? 3 : 4)*7;
    float sum=0.f, ssq=0.f;
    #pragma unroll
    for (int i=0;i<28;i++){
      if (i < NV){ float v = acc[i]; sum += v; ssq = fmaf(v,v,ssq); }
    }
    __shared__ float ls[20];
    if (threadIdx.x < 20) ls[threadIdx.x] = 0.f;
    __syncthreads();
    atomicAdd(&ls[oc], sum);
    atomicAdd(&ls[10+oc], ssq);
    __syncthreads();
    if (threadIdx.x < 20) atomicAdd(&ws[O_SUM2 + threadIdx.x], ls[threadIdx.x]);
  }
  // signed pooled extremum: half0 -> py 0,1; half1 -> py 2
  {
    const bool pos = (g2[oc] >= 0.f);
    const int npy = half ? 1 : 2;
    #pragma unroll
    for (int pl=0; pl<2; pl++){
      if (pl >= npy) continue;
      const int py = half ? 2 : pl;
      #pragma unroll
      for (int px=0;px<3;px++){
        float v00 = acc[(2*pl)*7   + 2*px], v01 = acc[(2*pl)*7   + 2*px+1];
        float v10 = acc[(2*pl+1)*7 + 2*px], v11 = acc[(2*pl+1)*7 + 2*px+1];
        float m4 = fmaxf(fmaxf(v00,v01), fmaxf(v10,v11));
        float n4 = fminf(fminf(v00,v01), fminf(v10,v11));
        ws[O_E2 + (n*9 + py*3 + px)*10 + oc] = pos ? m4 : n4;
      }
    }
  }
}

// in-place BN2 affine + relu on E2 -> pool2 [N][9][10]; accumulate the
// 10-channel mean + covariance moments of pool2 (conv3 1x1 => analytic BN3).
__global__ __launch_bounds__(256) void k_pool2fin(float* __restrict__ ws,
                                                  const float* __restrict__ g2,
                                                  const float* __restrict__ b2){
  __shared__ float smom[65];
  const int tid = threadIdx.x;
  if (tid < 65) smom[tid] = 0.f;
  __syncthreads();
  const float invM = 1.f/802816.f;
  const int gid = blockIdx.x*256 + tid;       // 147456 = N*9
  float* __restrict__ p = ws + O_E2 + gid*10;
  float xv[10];
  #pragma unroll
  for (int c=0;c<10;c++){
    float mean = ws[O_SUM2+c]*invM;
    float var  = ws[O_SSQ2+c]*invM - mean*mean;
    float sc = g2[c]*rsqrtf(var + kEPS);
    float tc = b2[c] - mean*sc;
    float v = fmaxf(fmaf(sc, p[c], tc), 0.f);
    xv[c] = v;
    p[c] = v;
  }
  float mu[10], sm[55];
  #pragma unroll
  for (int i=0;i<10;i++) mu[i] = xv[i];
  #pragma unroll
  for (int i=0;i<10;i++){
    #pragma unroll
    for (int j=i;j<10;j++) sm[i*10 - i*(i-1)/2 + (j-i)] = xv[i]*xv[j];
  }
  #pragma unroll
  for (int off=1; off<64; off<<=1){
    #pragma unroll
    for (int i=0;i<10;i++) mu[i] += __shfl_xor(mu[i], off);
    #pragma unroll
    for (int k=0;k<55;k++) sm[k] += __shfl_xor(sm[k], off);
  }
  if ((tid & 63) == 0){
    #pragma unroll
    for (int i=0;i<10;i++) atomicAdd(&smom[i], mu[i]);
    #pragma unroll
    for (int k=0;k<55;k++) atomicAdd(&smom[10+k], sm[k]);
  }
  __syncthreads();
  if (tid < 65) atomicAdd(&ws[O_MOM + tid], smom[tid]);
}

// BN3 finalize (from pool2 moments, conv3 linear) inlined + conv3(1x1) +
// BN3 + relu + avgpool(3x3) + fc -> theta[N,6]
__global__ __launch_bounds__(256) void k_theta(float* __restrict__ ws,
                                               const float* __restrict__ w3,
                                               const float* __restrict__ g3,
                                               const float* __restrict__ b3,
                                               const float* __restrict__ fw,
                                               const float* __restrict__ fb){
  __shared__ float s3[128], t3[128];
  const int tid = threadIdx.x;
  if (tid < 128){
    const int oc = tid;
    const float invM = 1.f/147456.f;
    float mu[10], w[10];
    #pragma unroll
    for (int i=0;i<10;i++) mu[i] = ws[O_MOM+i]*invM;
    #pragma unroll
    for (int i=0;i<10;i++) w[i] = w3[oc*10+i];
    float mean3 = 0.f;
    #pragma unroll
    for (int i=0;i<10;i++) mean3 += w[i]*mu[i];
    float var3 = 0.f;
    #pragma unroll
    for (int i=0;i<10;i++){
      #pragma unroll
      for (int j=i;j<10;j++){
        float Sij = ws[O_MOM+10 + i*10 - i*(i-1)/2 + (j-i)]*invM;
        float cov = Sij - mu[i]*mu[j];
        float coef = (i==j) ? 1.f : 2.f;
        var3 += coef * w[i] * w[j] * cov;
      }
    }
    var3 = fmaxf(var3, 0.f);
    float s = g3[oc]*rsqrtf(var3 + kEPS);
    s3[oc] = s;
    t3[oc] = b3[oc] - mean3*s;
  }
  __syncthreads();
  const int n = blockIdx.x*256 + tid;
  const float* __restrict__ ip = ws + O_E2 + n*90;   // pool2 [9 p][10 ic]
  float in[90];
  #pragma unroll
  for (int i=0;i<90;i++) in[i] = ip[i];
  float th[6];
  #pragma unroll
  for (int j=0;j<6;j++) th[j] = fb[j];
  for (int oc=0; oc<128; oc++){
    float s = s3[oc], t = t3[oc];
    float fsum = 0.f;
    #pragma unroll
    for (int p=0;p<9;p++){
      float v = 0.f;
      #pragma unroll
      for (int ic=0;ic<10;ic++) v = fmaf(w3[oc*10+ic], in[p*10+ic], v);
      fsum += fmaxf(fmaf(s,v,t), 0.f);
    }
    float feat = fsum * (1.f/9.f);
    #pragma unroll
    for (int j=0;j<6;j++) th[j] = fmaf(fw[j*128+oc], feat, th[j]);
  }
  float* __restrict__ op = ws + O_THETA + n*6;
  #pragma unroll
  for (int j=0;j<6;j++) op[j] = th[j];
}

// affine grid + bilinear sample; block <-> sample, image staged in LDS
__global__ __launch_bounds__(256) void k_sample(const float* __restrict__ x,
                                                const float* __restrict__ ws,
                                                float* __restrict__ out){
  const int n = blockIdx.x;
  __shared__ float sx[784];
  const int tid = threadIdx.x;
  if (tid < 196) ((float4*)sx)[tid] = ((const float4*)(x + n*784))[tid];
  __syncthreads();
  const float* __restrict__ th = ws + O_THETA + n*6;  // wave-uniform -> s_load
  const float t0=th[0], t1=th[1], t2=th[2], t3=th[3], t4=th[4], t5=th[5];
  float* __restrict__ op = out + n*784;
  for (int idx=tid; idx<784; idx+=256){
    int h = idx/28;
    int wcol = idx - 28*h;
    float gx = fmaf((float)wcol, 2.f/27.f, -1.f);
    float gy = fmaf((float)h,    2.f/27.f, -1.f);
    float ix = (fmaf(t0,gx,fmaf(t1,gy,t2)) + 1.f)*13.5f;
    float iy = (fmaf(t3,gx,fmaf(t4,gy,t5)) + 1.f)*13.5f;
    float x0f = floorf(ix), y0f = floorf(iy);
    float wx = ix - x0f, wy = iy - y0f;
    int x0 = min(max((int)x0f,0),27); int x1 = min(x0+1,27);
    int y0 = min(max((int)y0f,0),27); int y1 = min(y0+1,27);
    float v00 = sx[y0*28+x0], v01 = sx[y0*28+x1];
    float v10 = sx[y1*28+x0], v11 = sx[y1*28+x1];
    float top = v00*(1.f-wx) + v01*wx;
    float bot = v10*(1.f-wx) + v11*wx;
    op[idx] = top*(1.f-wy) + bot*wy;
  }
}

extern "C" void kernel_launch(void* const* d_in, const int* in_sizes, int n_in,
                              void* d_out, int out_size, void* d_ws, size_t ws_size,
                              hipStream_t stream){
  (void)in_sizes; (void)n_in; (void)out_size; (void)ws_size;
  const float* x  = (const float*)d_in[0];
  const float* w1 = (const float*)d_in[1];
  const float* g1 = (const float*)d_in[2];
  const float* b1 = (const float*)d_in[3];
  const float* w2 = (const float*)d_in[4];
  const float* g2 = (const float*)d_in[5];
  const float* b2 = (const float*)d_in[6];
  const float* w3 = (const float*)d_in[7];
  const float* g3 = (const float*)d_in[8];
  const float* b3 = (const float*)d_in[9];
  const float* fw = (const float*)d_in[10];
  const float* fb = (const float*)d_in[11];
  float* ws  = (float*)d_ws;
  float* out = (float*)d_out;

  hipLaunchKernelGGL(k_init,      dim3(8),     dim3(256), 0, stream, w2, ws);
  hipLaunchKernelGGL(k_conv1,     dim3(1024),  dim3(256), 0, stream, x, w1, g1, ws);
  hipLaunchKernelGGL(k_pool1fin,  dim3(2048),  dim3(256), 0, stream, ws, g1, b1);
  hipLaunchKernelGGL(k_conv2,     dim3(1280),  dim3(256), 0, stream, ws, g2);
  hipLaunchKernelGGL(k_pool2fin,  dim3(576),   dim3(256), 0, stream, ws, g2, b2);
  hipLaunchKernelGGL(k_theta,     dim3(64),    dim3(256), 0, stream, ws, w3, g3, b3, fw, fb);
  hipLaunchKernelGGL(k_sample,    dim3(16384), dim3(256), 0, stream, x, ws, out);
}

// Round 5
// 399.083 us; speedup vs baseline: 1.5406x; 1.5406x over previous
//
#include <hip/hip_runtime.h>

// ---------------------------------------------------------------------------
// Spatial transformer loc-net + bilinear sampler. N=16384, x:[N,1,28,28] f32.
// R2: single-pass convs (sign(BN scale)=sign(gamma) known a priori -> store
//     pooled extremum raw, finalize affine+relu later).
// R3: k_init race fix (zero only [0,104)).
// R4: conv1 weights in LDS (launch_bounds(256,4) in R3 forced VGPR=64 ->
//     scratch spill, 574MB fetch/dispatch, 2.6x slower. LDS weights cut
//     pressure without a cap). BN1 affine+relu folded into conv2's loads;
//     k_pool1fin deleted (-127MB RMW pass).
// ---------------------------------------------------------------------------

static constexpr float kEPS = 1e-5f;

// ws float offsets
#define O_SUM1 0
#define O_SSQ1 8
#define O_SUM2 16
#define O_SSQ2 26
#define O_MOM  36      // 10 means + 55 upper-tri second moments of pool2
#define O_W2T  104             // 2000 floats: w2 as [oc][ky][kx][ic]
#define O_THETA 2112           // 16384*6
#define O_E1   100864          // [N][11][11][8] raw pooled extremes (conv1)
#define O_E2   15960576        // [N][9][10]    raw pooled extremes (conv2)
// high-water: 17,435,136 floats = 69.7 MB

__global__ __launch_bounds__(256) void k_init(const float* __restrict__ w2,
                                              float* __restrict__ ws){
  int i = blockIdx.x*256 + threadIdx.x;
  if (i < 104) ws[i] = 0.f;            // stats region only — MUST not touch W2T
  if (i < 2000){
    int ic = i & 7;
    int r  = i >> 3;
    int kx = r % 5; r /= 5;
    int ky = r % 5; r /= 5;
    int oc = r;
    ws[O_W2T + i] = w2[(oc*8 + ic)*25 + ky*5 + kx];
  }
}

// conv1 7x7 [N,1,28,28]->[N,8,22,22], single pass: BN1 stats + signed pooled
// extremum -> E1 [N][11][11][8] (ic innermost). Weights in LDS ([c][49],
// stride 49 = 17 mod 32 -> 8 distinct banks, conflict-free broadcast).
__global__ __launch_bounds__(256) void k_conv1(const float* __restrict__ x,
                                               const float* __restrict__ w1,
                                               const float* __restrict__ g1,
                                               float* __restrict__ ws){
  __shared__ float sw[392];            // w1 is [8][49] flat already
  const int tid = threadIdx.x;
  for (int i = tid; i < 392; i += 256) sw[i] = w1[i];
  __syncthreads();
  const int gid = blockIdx.x*256 + tid;
  const int ph = gid & 1;          // which half of the 11 pooled rows
  const int c  = (gid >> 1) & 7;
  const int n  = gid >> 4;
  const float* __restrict__ xs = x + n*784;
  const float* __restrict__ wc = sw + c*49;
  const bool pos = (g1[c] >= 0.f);
  float sum=0.f, ssq=0.f;
  float* __restrict__ outp = ws + O_E1 + n*968 + c;   // interleaved base
  const int p0 = ph*6;
  const int p1 = ph ? 11 : 6;
  for (int p=p0; p<p1; p++){
    float a0[22], a1[22];
    #pragma unroll
    for (int i=0;i<22;i++){ a0[i]=0.f; a1[i]=0.f; }
    #pragma unroll
    for (int j=0;j<8;j++){            // input rows 2p..2p+7 feed conv rows 2p,2p+1
      float in[28];
      const float4* __restrict__ rp = (const float4*)(xs + (2*p+j)*28);
      #pragma unroll
      for (int q=0;q<7;q++){
        float4 v = rp[q];
        in[4*q]=v.x; in[4*q+1]=v.y; in[4*q+2]=v.z; in[4*q+3]=v.w;
      }
      if (j < 7){                     // ky = j for conv row 2p
        #pragma unroll
        for (int kx=0;kx<7;kx++){
          float wv = wc[j*7+kx];
          #pragma unroll
          for (int xo=0;xo<22;xo++) a0[xo] = fmaf(wv, in[xo+kx], a0[xo]);
        }
      }
      if (j >= 1){                    // ky = j-1 for conv row 2p+1
        #pragma unroll
        for (int kx=0;kx<7;kx++){
          float wv = wc[(j-1)*7+kx];
          #pragma unroll
          for (int xo=0;xo<22;xo++) a1[xo] = fmaf(wv, in[xo+kx], a1[xo]);
        }
      }
    }
    // stats over all conv outputs
    #pragma unroll
    for (int xo=0;xo<22;xo++){
      sum += a0[xo] + a1[xo];
      ssq = fmaf(a0[xo],a0[xo],ssq);
      ssq = fmaf(a1[xo],a1[xo],ssq);
    }
    // signed pooled extremum (sign of BN scale == sign of gamma, known now)
    #pragma unroll
    for (int px=0;px<11;px++){
      float m4 = fmaxf(fmaxf(a0[2*px],a0[2*px+1]), fmaxf(a1[2*px],a1[2*px+1]));
      float n4 = fminf(fminf(a0[2*px],a0[2*px+1]), fminf(a1[2*px],a1[2*px+1]));
      outp[(p*11+px)*8] = pos ? m4 : n4;
    }
  }
  // block-level stats reduction: lanes sharing c differ in bits {0,4,5}
  sum += __shfl_xor(sum,1);  ssq += __shfl_xor(ssq,1);
  sum += __shfl_xor(sum,16); ssq += __shfl_xor(ssq,16);
  sum += __shfl_xor(sum,32); ssq += __shfl_xor(ssq,32);
  __shared__ float ls[16];
  if (tid < 16) ls[tid] = 0.f;
  __syncthreads();
  int l = tid & 63;
  if ((l & 0x31) == 0){
    atomicAdd(&ls[l>>1], sum);
    atomicAdd(&ls[8 + (l>>1)], ssq);
  }
  __syncthreads();
  if (tid < 16) atomicAdd(&ws[O_SUM1 + tid], ls[tid]);
}

// conv2 5x5 [N,8,11,11]->[N,10,7,7], single pass. Reads RAW E1 extremes and
// applies BN1 affine+relu inline (s1/t1 recomputed per thread from stats —
// deletes the 127MB pool1fin RMW pass). BN2 stats + signed pooled extremum
// -> E2 [N][9][10]. Row-split: blocks<640 own conv rows 0..3, else 4..6.
__global__ __launch_bounds__(256) void k_conv2(float* __restrict__ ws,
                                               const float* __restrict__ g1,
                                               const float* __restrict__ b1,
                                               const float* __restrict__ g2){
  // BN1 scale/shift from conv1 stats (cheap, per-thread)
  float s1r[8], t1r[8];
  {
    const float invM1 = 1.f/7929856.f;
    #pragma unroll
    for (int c=0;c<8;c++){
      float mean = ws[O_SUM1+c]*invM1;
      float var  = ws[O_SSQ1+c]*invM1 - mean*mean;
      float sc = g1[c]*rsqrtf(var + kEPS);
      s1r[c] = sc; t1r[c] = b1[c] - mean*sc;
    }
  }
  const int blk = blockIdx.x;
  const int half = (blk >= 640) ? 1 : 0;
  const int gid = (blk - half*640)*256 + threadIdx.x;
  const int n = gid/10, oc = gid - 10*n;
  const int r0 = half*4;                 // first owned conv row
  const int nrows = half ? 7 : 8;        // input rows streamed
  const float* __restrict__ wt = ws + O_W2T + oc*200;
  const float* __restrict__ base = ws + O_E1 + n*968;   // RAW extremes
  float acc[28];
  #pragma unroll
  for (int i=0;i<28;i++) acc[i]=0.f;
  for (int jj=0; jj<nrows; ++jj){        // uniform loop
    const int iy = r0 + jj;
    float in[88];
    const float4* __restrict__ rp = (const float4*)(base + iy*88);
    #pragma unroll
    for (int q=0;q<22;q++){
      float4 v = rp[q];
      // BN1 affine + relu applied at load; ic = (4q+k)&7 is compile-time
      in[4*q+0] = fmaxf(fmaf(s1r[(4*q+0)&7], v.x, t1r[(4*q+0)&7]), 0.f);
      in[4*q+1] = fmaxf(fmaf(s1r[(4*q+1)&7], v.y, t1r[(4*q+1)&7]), 0.f);
      in[4*q+2] = fmaxf(fmaf(s1r[(4*q+2)&7], v.z, t1r[(4*q+2)&7]), 0.f);
      in[4*q+3] = fmaxf(fmaf(s1r[(4*q+3)&7], v.w, t1r[(4*q+3)&7]), 0.f);
    }
    #pragma unroll
    for (int ol=0; ol<4; ++ol){          // owned conv row (local)
      if (half && ol==3) continue;       // half1 owns 3 rows
      const int ky = jj - ol;            // uniform at runtime
      if (ky < 0 || ky > 4) continue;
      const float* __restrict__ wrow = wt + ky*40;
      #pragma unroll
      for (int kx=0;kx<5;kx++){
        float4 wa = *(const float4*)(wrow + kx*8);
        float4 wb = *(const float4*)(wrow + kx*8 + 4);
        #pragma unroll
        for (int ox=0;ox<7;ox++){
          float a = acc[ol*7+ox];
          a = fmaf(wa.x, in[(ox+kx)*8+0], a);
          a = fmaf(wa.y, in[(ox+kx)*8+1], a);
          a = fmaf(wa.z, in[(ox+kx)*8+2], a);
          a = fmaf(wa.w, in[(ox+kx)*8+3], a);
          a = fmaf(wb.x, in[(ox+kx)*8+4], a);
          a = fmaf(wb.y, in[(ox+kx)*8+5], a);
          a = fmaf(wb.z, in[(ox+kx)*8+6], a);
          a = fmaf(wb.w, in[(ox+kx)*8+7], a);
          acc[ol*7+ox] = a;
        }
      }
    }
  }
  // stats over owned conv rows
  {
    const int NV = (half ? 3 : 4)*7;
    float sum=0.f, ssq=0.f;
    #pragma unroll
    for (int i=0;i<28;i++){
      if (i < NV){ float v = acc[i]; sum += v; ssq = fmaf(v,v,ssq); }
    }
    __shared__ float ls[20];
    if (threadIdx.x < 20) ls[threadIdx.x] = 0.f;
    __syncthreads();
    atomicAdd(&ls[oc], sum);
    atomicAdd(&ls[10+oc], ssq);
    __syncthreads();
    if (threadIdx.x < 20) atomicAdd(&ws[O_SUM2 + threadIdx.x], ls[threadIdx.x]);
  }
  // signed pooled extremum: half0 -> py 0,1; half1 -> py 2
  {
    const bool pos = (g2[oc] >= 0.f);
    const int npy = half ? 1 : 2;
    #pragma unroll
    for (int pl=0; pl<2; pl++){
      if (pl >= npy) continue;
      const int py = half ? 2 : pl;
      #pragma unroll
      for (int px=0;px<3;px++){
        float v00 = acc[(2*pl)*7   + 2*px], v01 = acc[(2*pl)*7   + 2*px+1];
        float v10 = acc[(2*pl+1)*7 + 2*px], v11 = acc[(2*pl+1)*7 + 2*px+1];
        float m4 = fmaxf(fmaxf(v00,v01), fmaxf(v10,v11));
        float n4 = fminf(fminf(v00,v01), fminf(v10,v11));
        ws[O_E2 + (n*9 + py*3 + px)*10 + oc] = pos ? m4 : n4;
      }
    }
  }
}

// in-place BN2 affine + relu on E2 -> pool2 [N][9][10]; accumulate the
// 10-channel mean + covariance moments of pool2 (conv3 1x1 => analytic BN3).
__global__ __launch_bounds__(256) void k_pool2fin(float* __restrict__ ws,
                                                  const float* __restrict__ g2,
                                                  const float* __restrict__ b2){
  __shared__ float smom[65];
  const int tid = threadIdx.x;
  if (tid < 65) smom[tid] = 0.f;
  __syncthreads();
  const float invM = 1.f/802816.f;
  const int gid = blockIdx.x*256 + tid;       // 147456 = N*9
  float* __restrict__ p = ws + O_E2 + gid*10;
  float xv[10];
  #pragma unroll
  for (int c=0;c<10;c++){
    float mean = ws[O_SUM2+c]*invM;
    float var  = ws[O_SSQ2+c]*invM - mean*mean;
    float sc = g2[c]*rsqrtf(var + kEPS);
    float tc = b2[c] - mean*sc;
    float v = fmaxf(fmaf(sc, p[c], tc), 0.f);
    xv[c] = v;
    p[c] = v;
  }
  float mu[10], sm[55];
  #pragma unroll
  for (int i=0;i<10;i++) mu[i] = xv[i];
  #pragma unroll
  for (int i=0;i<10;i++){
    #pragma unroll
    for (int j=i;j<10;j++) sm[i*10 - i*(i-1)/2 + (j-i)] = xv[i]*xv[j];
  }
  #pragma unroll
  for (int off=1; off<64; off<<=1){
    #pragma unroll
    for (int i=0;i<10;i++) mu[i] += __shfl_xor(mu[i], off);
    #pragma unroll
    for (int k=0;k<55;k++) sm[k] += __shfl_xor(sm[k], off);
  }
  if ((tid & 63) == 0){
    #pragma unroll
    for (int i=0;i<10;i++) atomicAdd(&smom[i], mu[i]);
    #pragma unroll
    for (int k=0;k<55;k++) atomicAdd(&smom[10+k], sm[k]);
  }
  __syncthreads();
  if (tid < 65) atomicAdd(&ws[O_MOM + tid], smom[tid]);
}

// BN3 finalize (from pool2 moments, conv3 linear) inlined + conv3(1x1) +
// BN3 + relu + avgpool(3x3) + fc -> theta[N,6]
__global__ __launch_bounds__(256) void k_theta(float* __restrict__ ws,
                                               const float* __restrict__ w3,
                                               const float* __restrict__ g3,
                                               const float* __restrict__ b3,
                                               const float* __restrict__ fw,
                                               const float* __restrict__ fb){
  __shared__ float s3[128], t3[128];
  const int tid = threadIdx.x;
  if (tid < 128){
    const int oc = tid;
    const float invM = 1.f/147456.f;
    float mu[10], w[10];
    #pragma unroll
    for (int i=0;i<10;i++) mu[i] = ws[O_MOM+i]*invM;
    #pragma unroll
    for (int i=0;i<10;i++) w[i] = w3[oc*10+i];
    float mean3 = 0.f;
    #pragma unroll
    for (int i=0;i<10;i++) mean3 += w[i]*mu[i];
    float var3 = 0.f;
    #pragma unroll
    for (int i=0;i<10;i++){
      #pragma unroll
      for (int j=i;j<10;j++){
        float Sij = ws[O_MOM+10 + i*10 - i*(i-1)/2 + (j-i)]*invM;
        float cov = Sij - mu[i]*mu[j];
        float coef = (i==j) ? 1.f : 2.f;
        var3 += coef * w[i] * w[j] * cov;
      }
    }
    var3 = fmaxf(var3, 0.f);
    float s = g3[oc]*rsqrtf(var3 + kEPS);
    s3[oc] = s;
    t3[oc] = b3[oc] - mean3*s;
  }
  __syncthreads();
  const int n = blockIdx.x*256 + tid;
  const float* __restrict__ ip = ws + O_E2 + n*90;   // pool2 [9 p][10 ic]
  float in[90];
  #pragma unroll
  for (int i=0;i<90;i++) in[i] = ip[i];
  float th[6];
  #pragma unroll
  for (int j=0;j<6;j++) th[j] = fb[j];
  for (int oc=0; oc<128; oc++){
    float s = s3[oc], t = t3[oc];
    float fsum = 0.f;
    #pragma unroll
    for (int p=0;p<9;p++){
      float v = 0.f;
      #pragma unroll
      for (int ic=0;ic<10;ic++) v = fmaf(w3[oc*10+ic], in[p*10+ic], v);
      fsum += fmaxf(fmaf(s,v,t), 0.f);
    }
    float feat = fsum * (1.f/9.f);
    #pragma unroll
    for (int j=0;j<6;j++) th[j] = fmaf(fw[j*128+oc], feat, th[j]);
  }
  float* __restrict__ op = ws + O_THETA + n*6;
  #pragma unroll
  for (int j=0;j<6;j++) op[j] = th[j];
}

// affine grid + bilinear sample; block <-> sample, image staged in LDS
__global__ __launch_bounds__(256) void k_sample(const float* __restrict__ x,
                                                const float* __restrict__ ws,
                                                float* __restrict__ out){
  const int n = blockIdx.x;
  __shared__ float sx[784];
  const int tid = threadIdx.x;
  if (tid < 196) ((float4*)sx)[tid] = ((const float4*)(x + n*784))[tid];
  __syncthreads();
  const float* __restrict__ th = ws + O_THETA + n*6;  // wave-uniform -> s_load
  const float t0=th[0], t1=th[1], t2=th[2], t3=th[3], t4=th[4], t5=th[5];
  float* __restrict__ op = out + n*784;
  for (int idx=tid; idx<784; idx+=256){
    int h = idx/28;
    int wcol = idx - 28*h;
    float gx = fmaf((float)wcol, 2.f/27.f, -1.f);
    float gy = fmaf((float)h,    2.f/27.f, -1.f);
    float ix = (fmaf(t0,gx,fmaf(t1,gy,t2)) + 1.f)*13.5f;
    float iy = (fmaf(t3,gx,fmaf(t4,gy,t5)) + 1.f)*13.5f;
    float x0f = floorf(ix), y0f = floorf(iy);
    float wx = ix - x0f, wy = iy - y0f;
    int x0 = min(max((int)x0f,0),27); int x1 = min(x0+1,27);
    int y0 = min(max((int)y0f,0),27); int y1 = min(y0+1,27);
    float v00 = sx[y0*28+x0], v01 = sx[y0*28+x1];
    float v10 = sx[y1*28+x0], v11 = sx[y1*28+x1];
    float top = v00*(1.f-wx) + v01*wx;
    float bot = v10*(1.f-wx) + v11*wx;
    op[idx] = top*(1.f-wy) + bot*wy;
  }
}

extern "C" void kernel_launch(void* const* d_in, const int* in_sizes, int n_in,
                              void* d_out, int out_size, void* d_ws, size_t ws_size,
                              hipStream_t stream){
  (void)in_sizes; (void)n_in; (void)out_size; (void)ws_size;
  const float* x  = (const float*)d_in[0];
  const float* w1 = (const float*)d_in[1];
  const float* g1 = (const float*)d_in[2];
  const float* b1 = (const float*)d_in[3];
  const float* w2 = (const float*)d_in[4];
  const float* g2 = (const float*)d_in[5];
  const float* b2 = (const float*)d_in[6];
  const float* w3 = (const float*)d_in[7];
  const float* g3 = (const float*)d_in[8];
  const float* b3 = (const float*)d_in[9];
  const float* fw = (const float*)d_in[10];
  const float* fb = (const float*)d_in[11];
  float* ws  = (float*)d_ws;
  float* out = (float*)d_out;

  hipLaunchKernelGGL(k_init,      dim3(8),     dim3(256), 0, stream, w2, ws);
  hipLaunchKernelGGL(k_conv1,     dim3(1024),  dim3(256), 0, stream, x, w1, g1, ws);
  hipLaunchKernelGGL(k_conv2,     dim3(1280),  dim3(256), 0, stream, ws, g1, b1, g2);
  hipLaunchKernelGGL(k_pool2fin,  dim3(576),   dim3(256), 0, stream, ws, g2, b2);
  hipLaunchKernelGGL(k_theta,     dim3(64),    dim3(256), 0, stream, ws, w3, g3, b3, fw, fb);
  hipLaunchKernelGGL(k_sample,    dim3(16384), dim3(256), 0, stream, x, ws, out);
}

// Round 6
// 374.961 us; speedup vs baseline: 1.6397x; 1.0643x over previous
//
#include <hip/hip_runtime.h>

// ---------------------------------------------------------------------------
// Spatial transformer loc-net + bilinear sampler. N=16384, x:[N,1,28,28] f32.
// R2: single-pass convs (sign(BN scale)=sign(gamma) -> store pooled extremum
//     raw; finalize later). R3: k_init race fix. R4: LDS conv1 weights
//     (un-spill), BN1 folded into conv2 loads, pool1fin deleted.
// R5: conv1 was latency-bound (VALUBusy 60%, occ 3 waves/SIMD, load->use
//     global deps). Stage the block's 16 images in LDS (stride 788, rows
//     16B-aligned, banks spread) and feed the conv from ds_read_b128.
//     conv2: stage w2t in LDS (stride 216) — removes scattered per-lane
//     global weight streams.
// ---------------------------------------------------------------------------

static constexpr float kEPS = 1e-5f;

// ws float offsets
#define O_SUM1 0
#define O_SSQ1 8
#define O_SUM2 16
#define O_SSQ2 26
#define O_MOM  36      // 10 means + 55 upper-tri second moments of pool2
#define O_W2T  104             // 2000 floats: w2 as [oc][ky][kx][ic]
#define O_THETA 2112           // 16384*6
#define O_E1   100864          // [N][11][11][8] raw pooled extremes (conv1)
#define O_E2   15960576        // [N][9][10]    raw pooled extremes (conv2)
// high-water: 17,435,136 floats = 69.7 MB

__global__ __launch_bounds__(256) void k_init(const float* __restrict__ w2,
                                              float* __restrict__ ws){
  int i = blockIdx.x*256 + threadIdx.x;
  if (i < 104) ws[i] = 0.f;            // stats region only — MUST not touch W2T
  if (i < 2000){
    int ic = i & 7;
    int r  = i >> 3;
    int kx = r % 5; r /= 5;
    int ky = r % 5; r /= 5;
    int oc = r;
    ws[O_W2T + i] = w2[(oc*8 + ic)*25 + ky*5 + kx];
  }
}

// conv1 7x7 [N,1,28,28]->[N,8,22,22], single pass: BN1 stats + signed pooled
// extremum -> E1 [N][11][11][8]. Inputs staged in LDS: 16 images/block,
// per-sample stride 788 floats (rows stay 16B aligned; 788%32=20 spreads
// sample bases across banks). Weights in LDS too.
__global__ __launch_bounds__(256) void k_conv1(const float* __restrict__ x,
                                               const float* __restrict__ w1,
                                               const float* __restrict__ g1,
                                               float* __restrict__ ws){
  __shared__ float sx[16*788];         // 50432 B
  __shared__ float sw[392];            // w1 [8][49]
  const int tid = threadIdx.x;
  {
    const float4* __restrict__ gx = (const float4*)(x + (size_t)blockIdx.x*(16*784));
    float4* __restrict__ dx = (float4*)sx;
    #pragma unroll 4
    for (int f = tid; f < 3136; f += 256){   // 16 samples x 196 float4
      int s = f/196, i = f - s*196;
      dx[s*197 + i] = gx[f];
    }
    for (int i = tid; i < 392; i += 256) sw[i] = w1[i];
  }
  __syncthreads();
  const int ph = tid & 1;          // which half of the 11 pooled rows
  const int c  = (tid >> 1) & 7;
  const int nl = tid >> 4;         // local sample 0..15
  const int n  = blockIdx.x*16 + nl;
  const float* __restrict__ xs = sx + nl*788;
  const float* __restrict__ wc = sw + c*49;
  const bool pos = (g1[c] >= 0.f);
  float sum=0.f, ssq=0.f;
  float* __restrict__ outp = ws + O_E1 + n*968 + c;   // interleaved base
  const int p0 = ph*6;
  const int p1 = ph ? 11 : 6;
  for (int p=p0; p<p1; p++){
    float a0[22], a1[22];
    #pragma unroll
    for (int i=0;i<22;i++){ a0[i]=0.f; a1[i]=0.f; }
    #pragma unroll
    for (int j=0;j<8;j++){            // input rows 2p..2p+7 feed conv rows 2p,2p+1
      float in[28];
      const float4* __restrict__ rp = (const float4*)(xs + (2*p+j)*28);
      #pragma unroll
      for (int q=0;q<7;q++){
        float4 v = rp[q];
        in[4*q]=v.x; in[4*q+1]=v.y; in[4*q+2]=v.z; in[4*q+3]=v.w;
      }
      if (j < 7){                     // ky = j for conv row 2p
        #pragma unroll
        for (int kx=0;kx<7;kx++){
          float wv = wc[j*7+kx];
          #pragma unroll
          for (int xo=0;xo<22;xo++) a0[xo] = fmaf(wv, in[xo+kx], a0[xo]);
        }
      }
      if (j >= 1){                    // ky = j-1 for conv row 2p+1
        #pragma unroll
        for (int kx=0;kx<7;kx++){
          float wv = wc[(j-1)*7+kx];
          #pragma unroll
          for (int xo=0;xo<22;xo++) a1[xo] = fmaf(wv, in[xo+kx], a1[xo]);
        }
      }
    }
    // stats over all conv outputs
    #pragma unroll
    for (int xo=0;xo<22;xo++){
      sum += a0[xo] + a1[xo];
      ssq = fmaf(a0[xo],a0[xo],ssq);
      ssq = fmaf(a1[xo],a1[xo],ssq);
    }
    // signed pooled extremum (sign of BN scale == sign of gamma, known now)
    #pragma unroll
    for (int px=0;px<11;px++){
      float m4 = fmaxf(fmaxf(a0[2*px],a0[2*px+1]), fmaxf(a1[2*px],a1[2*px+1]));
      float n4 = fminf(fminf(a0[2*px],a0[2*px+1]), fminf(a1[2*px],a1[2*px+1]));
      outp[(p*11+px)*8] = pos ? m4 : n4;
    }
  }
  // block-level stats reduction: lanes sharing c differ in bits {0,4,5}
  sum += __shfl_xor(sum,1);  ssq += __shfl_xor(ssq,1);
  sum += __shfl_xor(sum,16); ssq += __shfl_xor(ssq,16);
  sum += __shfl_xor(sum,32); ssq += __shfl_xor(ssq,32);
  __shared__ float ls[16];
  if (tid < 16) ls[tid] = 0.f;
  __syncthreads();
  int l = tid & 63;
  if ((l & 0x31) == 0){
    atomicAdd(&ls[l>>1], sum);
    atomicAdd(&ls[8 + (l>>1)], ssq);
  }
  __syncthreads();
  if (tid < 16) atomicAdd(&ws[O_SUM1 + tid], ls[tid]);
}

// conv2 5x5 [N,8,11,11]->[N,10,7,7], single pass. Reads RAW E1 extremes and
// applies BN1 affine+relu inline. Weights from LDS (stride 216: oc*216%32
// spreads banks; rows stay 16B aligned). BN2 stats + signed pooled extremum
// -> E2 [N][9][10]. Row-split: blocks<640 own conv rows 0..3, else 4..6.
__global__ __launch_bounds__(256) void k_conv2(float* __restrict__ ws,
                                               const float* __restrict__ g1,
                                               const float* __restrict__ b1,
                                               const float* __restrict__ g2){
  __shared__ float sw2[2160];          // [10 oc][216] (200 used)
  for (int i = threadIdx.x; i < 2000; i += 256){
    int oc_ = i/200, r = i - oc_*200;
    sw2[oc_*216 + r] = ws[O_W2T + i];
  }
  __syncthreads();
  // BN1 scale/shift from conv1 stats (cheap, per-thread)
  float s1r[8], t1r[8];
  {
    const float invM1 = 1.f/7929856.f;
    #pragma unroll
    for (int c=0;c<8;c++){
      float mean = ws[O_SUM1+c]*invM1;
      float var  = ws[O_SSQ1+c]*invM1 - mean*mean;
      float sc = g1[c]*rsqrtf(var + kEPS);
      s1r[c] = sc; t1r[c] = b1[c] - mean*sc;
    }
  }
  const int blk = blockIdx.x;
  const int half = (blk >= 640) ? 1 : 0;
  const int gid = (blk - half*640)*256 + threadIdx.x;
  const int n = gid/10, oc = gid - 10*n;
  const int r0 = half*4;                 // first owned conv row
  const int nrows = half ? 7 : 8;        // input rows streamed
  const float* __restrict__ wt = sw2 + oc*216;
  const float* __restrict__ base = ws + O_E1 + n*968;   // RAW extremes
  float acc[28];
  #pragma unroll
  for (int i=0;i<28;i++) acc[i]=0.f;
  for (int jj=0; jj<nrows; ++jj){        // uniform loop
    const int iy = r0 + jj;
    float in[88];
    const float4* __restrict__ rp = (const float4*)(base + iy*88);
    #pragma unroll
    for (int q=0;q<22;q++){
      float4 v = rp[q];
      // BN1 affine + relu applied at load; ic = (4q+k)&7 is compile-time
      in[4*q+0] = fmaxf(fmaf(s1r[(4*q+0)&7], v.x, t1r[(4*q+0)&7]), 0.f);
      in[4*q+1] = fmaxf(fmaf(s1r[(4*q+1)&7], v.y, t1r[(4*q+1)&7]), 0.f);
      in[4*q+2] = fmaxf(fmaf(s1r[(4*q+2)&7], v.z, t1r[(4*q+2)&7]), 0.f);
      in[4*q+3] = fmaxf(fmaf(s1r[(4*q+3)&7], v.w, t1r[(4*q+3)&7]), 0.f);
    }
    #pragma unroll
    for (int ol=0; ol<4; ++ol){          // owned conv row (local)
      if (half && ol==3) continue;       // half1 owns 3 rows
      const int ky = jj - ol;            // uniform at runtime
      if (ky < 0 || ky > 4) continue;
      const float* __restrict__ wrow = wt + ky*40;
      #pragma unroll
      for (int kx=0;kx<5;kx++){
        float4 wa = *(const float4*)(wrow + kx*8);
        float4 wb = *(const float4*)(wrow + kx*8 + 4);
        #pragma unroll
        for (int ox=0;ox<7;ox++){
          float a = acc[ol*7+ox];
          a = fmaf(wa.x, in[(ox+kx)*8+0], a);
          a = fmaf(wa.y, in[(ox+kx)*8+1], a);
          a = fmaf(wa.z, in[(ox+kx)*8+2], a);
          a = fmaf(wa.w, in[(ox+kx)*8+3], a);
          a = fmaf(wb.x, in[(ox+kx)*8+4], a);
          a = fmaf(wb.y, in[(ox+kx)*8+5], a);
          a = fmaf(wb.z, in[(ox+kx)*8+6], a);
          a = fmaf(wb.w, in[(ox+kx)*8+7], a);
          acc[ol*7+ox] = a;
        }
      }
    }
  }
  // stats over owned conv rows
  {
    const int NV = (half ? 3 : 4)*7;
    float sum=0.f, ssq=0.f;
    #pragma unroll
    for (int i=0;i<28;i++){
      if (i < NV){ float v = acc[i]; sum += v; ssq = fmaf(v,v,ssq); }
    }
    __shared__ float ls[20];
    if (threadIdx.x < 20) ls[threadIdx.x] = 0.f;
    __syncthreads();
    atomicAdd(&ls[oc], sum);
    atomicAdd(&ls[10+oc], ssq);
    __syncthreads();
    if (threadIdx.x < 20) atomicAdd(&ws[O_SUM2 + threadIdx.x], ls[threadIdx.x]);
  }
  // signed pooled extremum: half0 -> py 0,1; half1 -> py 2
  {
    const bool pos = (g2[oc] >= 0.f);
    const int npy = half ? 1 : 2;
    #pragma unroll
    for (int pl=0; pl<2; pl++){
      if (pl >= npy) continue;
      const int py = half ? 2 : pl;
      #pragma unroll
      for (int px=0;px<3;px++){
        float v00 = acc[(2*pl)*7   + 2*px], v01 = acc[(2*pl)*7   + 2*px+1];
        float v10 = acc[(2*pl+1)*7 + 2*px], v11 = acc[(2*pl+1)*7 + 2*px+1];
        float m4 = fmaxf(fmaxf(v00,v01), fmaxf(v10,v11));
        float n4 = fminf(fminf(v00,v01), fminf(v10,v11));
        ws[O_E2 + (n*9 + py*3 + px)*10 + oc] = pos ? m4 : n4;
      }
    }
  }
}

// in-place BN2 affine + relu on E2 -> pool2 [N][9][10]; accumulate the
// 10-channel mean + covariance moments of pool2 (conv3 1x1 => analytic BN3).
__global__ __launch_bounds__(256) void k_pool2fin(float* __restrict__ ws,
                                                  const float* __restrict__ g2,
                                                  const float* __restrict__ b2){
  __shared__ float smom[65];
  const int tid = threadIdx.x;
  if (tid < 65) smom[tid] = 0.f;
  __syncthreads();
  const float invM = 1.f/802816.f;
  const int gid = blockIdx.x*256 + tid;       // 147456 = N*9
  float* __restrict__ p = ws + O_E2 + gid*10;
  float xv[10];
  #pragma unroll
  for (int c=0;c<10;c++){
    float mean = ws[O_SUM2+c]*invM;
    float var  = ws[O_SSQ2+c]*invM - mean*mean;
    float sc = g2[c]*rsqrtf(var + kEPS);
    float tc = b2[c] - mean*sc;
    float v = fmaxf(fmaf(sc, p[c], tc), 0.f);
    xv[c] = v;
    p[c] = v;
  }
  float mu[10], sm[55];
  #pragma unroll
  for (int i=0;i<10;i++) mu[i] = xv[i];
  #pragma unroll
  for (int i=0;i<10;i++){
    #pragma unroll
    for (int j=i;j<10;j++) sm[i*10 - i*(i-1)/2 + (j-i)] = xv[i]*xv[j];
  }
  #pragma unroll
  for (int off=1; off<64; off<<=1){
    #pragma unroll
    for (int i=0;i<10;i++) mu[i] += __shfl_xor(mu[i], off);
    #pragma unroll
    for (int k=0;k<55;k++) sm[k] += __shfl_xor(sm[k], off);
  }
  if ((tid & 63) == 0){
    #pragma unroll
    for (int i=0;i<10;i++) atomicAdd(&smom[i], mu[i]);
    #pragma unroll
    for (int k=0;k<55;k++) atomicAdd(&smom[10+k], sm[k]);
  }
  __syncthreads();
  if (tid < 65) atomicAdd(&ws[O_MOM + tid], smom[tid]);
}

// BN3 finalize (from pool2 moments, conv3 linear) inlined + conv3(1x1) +
// BN3 + relu + avgpool(3x3) + fc -> theta[N,6]
__global__ __launch_bounds__(256) void k_theta(float* __restrict__ ws,
                                               const float* __restrict__ w3,
                                               const float* __restrict__ g3,
                                               const float* __restrict__ b3,
                                               const float* __restrict__ fw,
                                               const float* __restrict__ fb){
  __shared__ float s3[128], t3[128];
  const int tid = threadIdx.x;
  if (tid < 128){
    const int oc = tid;
    const float invM = 1.f/147456.f;
    float mu[10], w[10];
    #pragma unroll
    for (int i=0;i<10;i++) mu[i] = ws[O_MOM+i]*invM;
    #pragma unroll
    for (int i=0;i<10;i++) w[i] = w3[oc*10+i];
    float mean3 = 0.f;
    #pragma unroll
    for (int i=0;i<10;i++) mean3 += w[i]*mu[i];
    float var3 = 0.f;
    #pragma unroll
    for (int i=0;i<10;i++){
      #pragma unroll
      for (int j=i;j<10;j++){
        float Sij = ws[O_MOM+10 + i*10 - i*(i-1)/2 + (j-i)]*invM;
        float cov = Sij - mu[i]*mu[j];
        float coef = (i==j) ? 1.f : 2.f;
        var3 += coef * w[i] * w[j] * cov;
      }
    }
    var3 = fmaxf(var3, 0.f);
    float s = g3[oc]*rsqrtf(var3 + kEPS);
    s3[oc] = s;
    t3[oc] = b3[oc] - mean3*s;
  }
  __syncthreads();
  const int n = blockIdx.x*256 + tid;
  const float* __restrict__ ip = ws + O_E2 + n*90;   // pool2 [9 p][10 ic]
  float in[90];
  #pragma unroll
  for (int i=0;i<90;i++) in[i] = ip[i];
  float th[6];
  #pragma unroll
  for (int j=0;j<6;j++) th[j] = fb[j];
  for (int oc=0; oc<128; oc++){
    float s = s3[oc], t = t3[oc];
    float fsum = 0.f;
    #pragma unroll
    for (int p=0;p<9;p++){
      float v = 0.f;
      #pragma unroll
      for (int ic=0;ic<10;ic++) v = fmaf(w3[oc*10+ic], in[p*10+ic], v);
      fsum += fmaxf(fmaf(s,v,t), 0.f);
    }
    float feat = fsum * (1.f/9.f);
    #pragma unroll
    for (int j=0;j<6;j++) th[j] = fmaf(fw[j*128+oc], feat, th[j]);
  }
  float* __restrict__ op = ws + O_THETA + n*6;
  #pragma unroll
  for (int j=0;j<6;j++) op[j] = th[j];
}

// affine grid + bilinear sample; block <-> sample, image staged in LDS
__global__ __launch_bounds__(256) void k_sample(const float* __restrict__ x,
                                                const float* __restrict__ ws,
                                                float* __restrict__ out){
  const int n = blockIdx.x;
  __shared__ float sx[784];
  const int tid = threadIdx.x;
  if (tid < 196) ((float4*)sx)[tid] = ((const float4*)(x + n*784))[tid];
  __syncthreads();
  const float* __restrict__ th = ws + O_THETA + n*6;  // wave-uniform -> s_load
  const float t0=th[0], t1=th[1], t2=th[2], t3=th[3], t4=th[4], t5=th[5];
  float* __restrict__ op = out + n*784;
  for (int idx=tid; idx<784; idx+=256){
    int h = idx/28;
    int wcol = idx - 28*h;
    float gx = fmaf((float)wcol, 2.f/27.f, -1.f);
    float gy = fmaf((float)h,    2.f/27.f, -1.f);
    float ix = (fmaf(t0,gx,fmaf(t1,gy,t2)) + 1.f)*13.5f;
    float iy = (fmaf(t3,gx,fmaf(t4,gy,t5)) + 1.f)*13.5f;
    float x0f = floorf(ix), y0f = floorf(iy);
    float wx = ix - x0f, wy = iy - y0f;
    int x0 = min(max((int)x0f,0),27); int x1 = min(x0+1,27);
    int y0 = min(max((int)y0f,0),27); int y1 = min(y0+1,27);
    float v00 = sx[y0*28+x0], v01 = sx[y0*28+x1];
    float v10 = sx[y1*28+x0], v11 = sx[y1*28+x1];
    float top = v00*(1.f-wx) + v01*wx;
    float bot = v10*(1.f-wx) + v11*wx;
    op[idx] = top*(1.f-wy) + bot*wy;
  }
}

extern "C" void kernel_launch(void* const* d_in, const int* in_sizes, int n_in,
                              void* d_out, int out_size, void* d_ws, size_t ws_size,
                              hipStream_t stream){
  (void)in_sizes; (void)n_in; (void)out_size; (void)ws_size;
  const float* x  = (const float*)d_in[0];
  const float* w1 = (const float*)d_in[1];
  const float* g1 = (const float*)d_in[2];
  const float* b1 = (const float*)d_in[3];
  const float* w2 = (const float*)d_in[4];
  const float* g2 = (const float*)d_in[5];
  const float* b2 = (const float*)d_in[6];
  const float* w3 = (const float*)d_in[7];
  const float* g3 = (const float*)d_in[8];
  const float* b3 = (const float*)d_in[9];
  const float* fw = (const float*)d_in[10];
  const float* fb = (const float*)d_in[11];
  float* ws  = (float*)d_ws;
  float* out = (float*)d_out;

  hipLaunchKernelGGL(k_init,      dim3(8),     dim3(256), 0, stream, w2, ws);
  hipLaunchKernelGGL(k_conv1,     dim3(1024),  dim3(256), 0, stream, x, w1, g1, ws);
  hipLaunchKernelGGL(k_conv2,     dim3(1280),  dim3(256), 0, stream, ws, g1, b1, g2);
  hipLaunchKernelGGL(k_pool2fin,  dim3(576),   dim3(256), 0, stream, ws, g2, b2);
  hipLaunchKernelGGL(k_theta,     dim3(64),    dim3(256), 0, stream, ws, w3, g3, b3, fw, fb);
  hipLaunchKernelGGL(k_sample,    dim3(16384), dim3(256), 0, stream, x, ws, out);
}